// Round 7
// baseline (465.561 us; speedup 1.0000x reference)
//
#include <hip/hip_runtime.h>
#include <hip/hip_fp16.h>

typedef _Float16 f16;
typedef __attribute__((ext_vector_type(8))) _Float16 f16x8;
typedef __attribute__((ext_vector_type(4))) _Float16 f16x4;
typedef __attribute__((ext_vector_type(4))) float f32x4;

#define BM 256
#define BN 256
#define BK 64

__device__ __forceinline__ void gll16(const void* src, void* dst) {
  __builtin_amdgcn_global_load_lds((const __attribute__((address_space(1))) void*)src,
                                   (__attribute__((address_space(3))) void*)dst,
                                   16, 0, 0);
}

// C[m,n] = sum_k A[m,k] * B[n,k]  ("BT" form). 8-phase m201-style schedule (R5).
// CVT=false: fp16 operands staged via global_load_lds, counted vmcnt(4) at ph4/ph8.
// CVT=true : fp32 operands, T14 split staging: LOAD (4x dwordx4 -> regs) issued at
//   phase P-2; at phase P: cvt + ds_write (published by the phase's own lgkmcnt(0),
//   one barrier before any reader — identical slot timing to the gll path).
//   Pending regs P0/P1 alternate phase parity; all indices static (rule #20).
// Swizzle: linear slot s of row r holds global slot s^(r&7) (0 conflicts, R3/R5).
// MODE 0: C fp16   MODE 1: P=exp(acc*scale+mask) fp16 + row-sum partials
// MODE 2: C fp32 = acc / lvec[z*M+row]
template<int MODE, bool CVT>
__global__ __launch_bounds__(512, 2)
void gemm_bt(const void* __restrict__ Aall, const void* __restrict__ Ball,
             void* __restrict__ Call,
             int M, int N, int K, int lda, int ldb, int ldc,
             long strideA, long strideB, long strideC,
             const float* __restrict__ maskAll, long strideMask,
             float* __restrict__ lvec, float scale)
{
  __shared__ __align__(16) f16 smA[2][BM * BK];   // 2 x 32 KB
  __shared__ __align__(16) f16 smB[2][BN * BK];   // 2 x 32 KB  -> 128 KiB

  // T1: bijective XCD-aware remap (all grids have nwg % 8 == 0)
  unsigned gx = gridDim.x, gy = gridDim.y;
  unsigned id = (blockIdx.z * gy + blockIdx.y) * gx + blockIdx.x;
  unsigned nwg = gx * gy * gridDim.z;
  unsigned swz = (id & 7) * (nwg >> 3) + (id >> 3);
  unsigned bx = swz % gx, rem = swz / gx;
  unsigned by = rem % gy, bz = rem / gy;

  const int z = bz;
  const void* A = (const char*)Aall + (long)z * strideA * (CVT ? 4 : 2);
  const void* B = (const char*)Ball + (long)z * strideB * (CVT ? 4 : 2);

  const int tid  = threadIdx.x;
  const int wid  = tid >> 6;
  const int lane = tid & 63;
  const int wm = wid >> 2;        // 0..1 -> 128 rows of C
  const int wn = wid & 3;         // 0..3 -> 64 cols of C
  const int lr = lane & 15;
  const int g  = lane >> 4;       // k-slot 0..3 (8 f16 each)

  const long brow = (long)by * BM;
  const long bcol = (long)bx * BN;
  const int  nt   = K / BK;       // >= 4, even

  f32x4 acc[8][4] = {};
  f16x8 af[8], bf[8];
  float4 P0[4], P1[4];            // pending CVT loads (2 chunks x 2 float4 each)

  // ---- staging helpers. chunk c: row=c>>3, linear slot=c&7, global slot ^(r&7).
  auto stage_half = [&](f16* dst, const void* srcBase, long prow, int ld_, int rowOff, int t) {
    #pragma unroll
    for (int i = 0; i < 2; ++i) {
      int c  = i * 512 + tid;
      int r  = c >> 3;
      int sl = (c & 7) ^ (r & 7);
      gll16((const f16*)srcBase + (prow + rowOff + r) * (long)ld_ + t * BK + sl * 8,
            dst + rowOff * BK + c * 8);
    }
  };
  auto ldhalf = [&](float4* P, const void* srcBase, long prow, int ld_, int rowOff, int t) {
    #pragma unroll
    for (int i = 0; i < 2; ++i) {
      int c  = i * 512 + tid;
      int r  = c >> 3;
      int sl = (c & 7) ^ (r & 7);
      const float* s = (const float*)srcBase + (prow + rowOff + r) * (long)ld_ + t * BK + sl * 8;
      P[i * 2]     = *(const float4*)s;
      P[i * 2 + 1] = *(const float4*)(s + 4);
    }
  };
  auto wrhalf = [&](const float4* P, f16* dst, int rowOff) {
    #pragma unroll
    for (int i = 0; i < 2; ++i) {
      int c = i * 512 + tid;
      float4 lo = P[i * 2], hi = P[i * 2 + 1];
      f16x8 o;
      o[0] = (f16)lo.x; o[1] = (f16)lo.y; o[2] = (f16)lo.z; o[3] = (f16)lo.w;
      o[4] = (f16)hi.x; o[5] = (f16)hi.y; o[6] = (f16)hi.z; o[7] = (f16)hi.w;
      *(f16x8*)(dst + rowOff * BK + c * 8) = o;
    }
  };
  auto rdA = [&](const f16* sa, int mh) {
    #pragma unroll
    for (int fm = 0; fm < 4; ++fm)
      #pragma unroll
      for (int ks = 0; ks < 2; ++ks) {
        int r = wm * 128 + mh * 64 + fm * 16 + lr;
        af[fm * 2 + ks] = *(const f16x8*)(sa + r * BK + ((ks * 4 + g) ^ (r & 7)) * 8);
      }
  };
  auto rdB = [&](const f16* sb, int nh) {
    #pragma unroll
    for (int fn = 0; fn < 2; ++fn)
      #pragma unroll
      for (int ks = 0; ks < 2; ++ks) {
        int r = wn * 64 + (nh * 2 + fn) * 16 + lr;
        bf[(nh * 2 + fn) * 2 + ks] = *(const f16x8*)(sb + r * BK + ((ks * 4 + g) ^ (r & 7)) * 8);
      }
  };
  auto sync_mfma = [&](int fm0, int fn0) {
    __builtin_amdgcn_s_barrier();
    asm volatile("s_waitcnt lgkmcnt(0)" ::: "memory");
    __builtin_amdgcn_sched_barrier(0);
    __builtin_amdgcn_s_setprio(1);
    #pragma unroll
    for (int fm = 0; fm < 4; ++fm)
      #pragma unroll
      for (int fn = 0; fn < 2; ++fn)
        #pragma unroll
        for (int ks = 0; ks < 2; ++ks)
          acc[fm0 + fm][fn0 + fn] = __builtin_amdgcn_mfma_f32_16x16x32_f16(
              af[fm * 2 + ks], bf[(fn0 + fn) * 2 + ks], acc[fm0 + fm][fn0 + fn], 0, 0, 0);
    __builtin_amdgcn_s_setprio(0);
    __builtin_amdgcn_s_barrier();
  };

  // ---- prologue: tile0 (A,B) + tile1 B staged; A(1) flows through pend P1/P0.
  if constexpr (CVT) {
    float4 T[4];
    ldhalf(T, A, brow, lda, 0, 0);   wrhalf(T, smA[0], 0);
    ldhalf(T, A, brow, lda, 128, 0); wrhalf(T, smA[0], 128);
    ldhalf(T, B, bcol, ldb, 0, 0);   wrhalf(T, smB[0], 0);
    ldhalf(T, B, bcol, ldb, 128, 0); wrhalf(T, smB[0], 128);
    ldhalf(T, B, bcol, ldb, 0, 1);   wrhalf(T, smB[1], 0);
    ldhalf(T, B, bcol, ldb, 128, 1); wrhalf(T, smB[1], 128);
    ldhalf(P1, A, brow, lda, 0, 1);    // A(1)hi -> written at ph1
    ldhalf(P0, A, brow, lda, 128, 1);  // A(1)lo -> written at ph2
    asm volatile("s_waitcnt lgkmcnt(0)" ::: "memory");
    __builtin_amdgcn_s_barrier();
  } else {
    stage_half(smA[0], A, brow, lda, 0, 0);
    stage_half(smA[0], A, brow, lda, 128, 0);
    stage_half(smB[0], B, bcol, ldb, 0, 0);
    stage_half(smB[0], B, bcol, ldb, 128, 0);
    stage_half(smB[1], B, bcol, ldb, 0, 1);
    stage_half(smB[1], B, bcol, ldb, 128, 1);
    asm volatile("s_waitcnt vmcnt(4)" ::: "memory");
    __builtin_amdgcn_s_barrier();
  }

  const int niter = nt / 2;
  for (int i = 0; i < niter; ++i) {
    const bool last = (i == niter - 1);
    const int t1 = 2 * i + 1, t2 = 2 * i + 2, t3 = 2 * i + 3;
    const int t2c = t2 < nt ? t2 : nt - 1;       // clamped load targets (never written)
    const int t3c = t3 < nt ? t3 : nt - 1;

    // ph1: reads buf0 A-hi + B n0-1 ; publish A(t1)hi ; load B(t2)hi
    rdA(smA[0], 0); rdB(smB[0], 0);
    if constexpr (CVT) { wrhalf(P1, smA[1], 0); ldhalf(P1, B, bcol, ldb, 0, t2c); }
    else stage_half(smA[1], A, brow, lda, 0, t1);
    sync_mfma(0, 0);
    // ph2: reads buf0 B n2-3 ; publish A(t1)lo ; load B(t2)lo
    rdB(smB[0], 1);
    if constexpr (CVT) { wrhalf(P0, smA[1], 128); ldhalf(P0, B, bcol, ldb, 128, t2c); }
    else stage_half(smA[1], A, brow, lda, 128, t1);
    sync_mfma(0, 2);
    // ph3: reads buf0 A-lo ; publish B(t2)hi ; load A(t2)hi
    rdA(smA[0], 1);
    if constexpr (CVT) { if (t2 < nt) wrhalf(P1, smB[0], 0); ldhalf(P1, A, brow, lda, 0, t2c); }
    else { if (t2 < nt) stage_half(smB[0], B, bcol, ldb, 0, t2); }
    sync_mfma(4, 2);
    // ph4: publish B(t2)lo ; load A(t2)lo ; (gll: counted wait)
    if constexpr (CVT) { if (t2 < nt) wrhalf(P0, smB[0], 128); ldhalf(P0, A, brow, lda, 128, t2c); }
    else {
      if (t2 < nt) stage_half(smB[0], B, bcol, ldb, 128, t2);
      if (!last) { asm volatile("s_waitcnt vmcnt(4)" ::: "memory"); }
      else       { asm volatile("s_waitcnt vmcnt(0)" ::: "memory"); }
    }
    sync_mfma(4, 0);
    // ph5: reads buf1 A-hi + B n0-1 ; publish A(t2)hi ; load B(t3)hi
    rdA(smA[1], 0); rdB(smB[1], 0);
    if constexpr (CVT) { if (t2 < nt) wrhalf(P1, smA[0], 0); ldhalf(P1, B, bcol, ldb, 0, t3c); }
    else { if (t2 < nt) stage_half(smA[0], A, brow, lda, 0, t2); }
    sync_mfma(0, 0);
    // ph6: reads buf1 B n2-3 ; publish A(t2)lo ; load B(t3)lo
    rdB(smB[1], 1);
    if constexpr (CVT) { if (t2 < nt) wrhalf(P0, smA[0], 128); ldhalf(P0, B, bcol, ldb, 128, t3c); }
    else { if (t2 < nt) stage_half(smA[0], A, brow, lda, 128, t2); }
    sync_mfma(0, 2);
    // ph7: reads buf1 A-lo ; publish B(t3)hi ; load A(next t1)hi
    rdA(smA[1], 1);
    if constexpr (CVT) { if (t3 < nt) wrhalf(P1, smB[1], 0); ldhalf(P1, A, brow, lda, 0, t3c); }
    else { if (t3 < nt) stage_half(smB[1], B, bcol, ldb, 0, t3); }
    sync_mfma(4, 2);
    // ph8: publish B(t3)lo ; load A(next t1)lo ; (gll: counted wait)
    if constexpr (CVT) { if (t3 < nt) wrhalf(P0, smB[1], 128); ldhalf(P0, A, brow, lda, 128, t3c); }
    else {
      if (t3 < nt) stage_half(smB[1], B, bcol, ldb, 128, t3);
      if (!last) { asm volatile("s_waitcnt vmcnt(4)" ::: "memory"); }
    }
    sync_mfma(4, 0);
  }

  // C/D layout (m89-verified): col = lane&15, row = (lane>>4)*4 + reg
  const int rb = (lane >> 4) * 4;

  if (MODE == 0) {
    f16* C = (f16*)Call + (long)z * strideC;
    #pragma unroll
    for (int m = 0; m < 8; ++m)
      #pragma unroll
      for (int j = 0; j < 4; ++j) {
        long grow = brow + wm * 128 + m * 16 + rb + j;
        #pragma unroll
        for (int n = 0; n < 4; ++n) {
          long gcol = bcol + wn * 64 + n * 16 + lr;
          C[grow * ldc + gcol] = (f16)acc[m][n][j];
        }
      }
  } else if (MODE == 1) {
    f16* C = (f16*)Call + (long)z * strideC;
    const float* mask = maskAll + (long)z * strideMask;
    #pragma unroll
    for (int m = 0; m < 8; ++m)
      #pragma unroll
      for (int j = 0; j < 4; ++j) {
        long grow = brow + wm * 128 + m * 16 + rb + j;
        float s = 0.f;
        #pragma unroll
        for (int n = 0; n < 4; ++n) {
          long gcol = bcol + wn * 64 + n * 16 + lr;
          float p = __expf(acc[m][n][j] * scale + mask[grow * ldc + gcol]);
          C[grow * ldc + gcol] = (f16)p;
          s += p;
        }
        s += __shfl_xor(s, 1);
        s += __shfl_xor(s, 2);
        s += __shfl_xor(s, 4);
        s += __shfl_xor(s, 8);
        if (lr == 0)
          lvec[((long)z * M + grow) * 32 + bx * 4 + wn] = s;
      }
  } else {
    float* C = (float*)Call + (long)z * strideC;
    #pragma unroll
    for (int m = 0; m < 8; ++m)
      #pragma unroll
      for (int j = 0; j < 4; ++j) {
        long grow = brow + wm * 128 + m * 16 + rb + j;
        float inv = 1.0f / lvec[(long)z * M + grow];
        #pragma unroll
        for (int n = 0; n < 4; ++n) {
          long gcol = bcol + wn * 64 + n * 16 + lr;
          C[grow * ldc + gcol] = acc[m][n][j] * inv;
        }
      }
  }
}

__global__ void reduce_l(const float* __restrict__ lpart, float* __restrict__ lsum, int n) {
  int i = blockIdx.x * blockDim.x + threadIdx.x;
  if (i < n) {
    float s = 0.f;
    #pragma unroll
    for (int j = 0; j < 32; ++j) s += lpart[(long)i * 32 + j];
    lsum[i] = s;
  }
}

extern "C" void kernel_launch(void* const* d_in, const int* in_sizes, int n_in,
                              void* d_out, int out_size, void* d_ws, size_t ws_size,
                              hipStream_t stream)
{
  const float* q    = (const float*)d_in[0];
  const float* k    = (const float*)d_in[1];
  const float* v    = (const float*)d_in[2];
  const float* mask = (const float*)d_in[3];
  const float* Wq   = (const float*)d_in[4];
  const float* Wk   = (const float*)d_in[5];
  const float* Wv   = (const float*)d_in[6];
  float* out = (float*)d_out;
  char*  ws  = (char*)d_ws;

  // workspace layout (bytes)
  f16*   Pm    = (f16*)(ws + 0);           // 64 MB
  f16*   qp    = (f16*)(ws + 67108864);    // 32 MB
  f16*   kp    = (f16*)(ws + 100663296);   // 32 MB
  f16*   vpT   = (f16*)(ws + 134217728);   // 32 MB (stored H x J, transposed)
  float* lpart = (float*)(ws + 167772160); // 2 MB
  float* lsum  = (float*)(ws + 169869312); // 64 KB

  const long L = 2048, J = 2048, D = 1024, H = 1024;

  // 1) projections with fused fp32->fp16 (T14 split CVT staging)
  // qp[bl,h] = sum_d q[bl,d] * Wq[h,d]     M=16384 N=1024 K=1024
  gemm_bt<0, true><<<dim3(1024 / BN, 16384 / BM, 1), dim3(512), 0, stream>>>(
      q, Wq, qp, 16384, 1024, 1024, 1024, 1024, 1024,
      0, 0, 0, nullptr, 0, nullptr, 0.f);
  // kp[bj,h] = sum_d k[bj,d] * Wk[h,d]
  gemm_bt<0, true><<<dim3(1024 / BN, 16384 / BM, 1), dim3(512), 0, stream>>>(
      k, Wk, kp, 16384, 1024, 1024, 1024, 1024, 1024,
      0, 0, 0, nullptr, 0, nullptr, 0.f);
  // vpT[b][h,j] = sum_d Wv[h,d] * v[b][j,d]   M=1024 N=2048 K=1024, batched over b
  gemm_bt<0, true><<<dim3(2048 / BN, 1024 / BM, 8), dim3(512), 0, stream>>>(
      Wv, v, vpT, 1024, 2048, 1024, 1024, 1024, 2048,
      0, J * D, H * J, nullptr, 0, nullptr, 0.f);

  // 2) P[b][l,j] = exp(qp.kp^T / 32 + mask), fp16, + row-sum partials
  gemm_bt<1, false><<<dim3(2048 / BN, 2048 / BM, 8), dim3(512), 0, stream>>>(
      qp, kp, Pm, 2048, 2048, 1024, 1024, 1024, 2048,
      L * H, J * H, L * J, mask, L * J, lpart, 0.03125f);

  reduce_l<<<dim3(16384 / 256), dim3(256), 0, stream>>>(lpart, lsum, 16384);

  // 3) out[b][l,h] = (sum_j P[l,j] * vpT[h,j]) / l[b,l]   M=2048 N=1024 K=2048
  gemm_bt<2, false><<<dim3(1024 / BN, 2048 / BM, 8), dim3(512), 0, stream>>>(
      Pm, vpT, out, 2048, 1024, 2048, 2048, 2048, 1024,
      L * J, H * J, L * H, nullptr, 0, lsum, 0.f);
}

// Round 8
// 359.361 us; speedup vs baseline: 1.2955x; 1.2955x over previous
//
#include <hip/hip_runtime.h>
#include <hip/hip_fp16.h>

typedef _Float16 f16;
typedef __attribute__((ext_vector_type(8))) _Float16 f16x8;
typedef __attribute__((ext_vector_type(4))) _Float16 f16x4;
typedef __attribute__((ext_vector_type(4))) float f32x4;

#define BM 128
#define BN 128
#define BK 64

__device__ __forceinline__ void gll16(const void* src, void* dst) {
  __builtin_amdgcn_global_load_lds((const __attribute__((address_space(1))) void*)src,
                                   (__attribute__((address_space(3))) void*)dst,
                                   16, 0, 0);
}

// C[m,n] = sum_k A[m,k] * B[n,k]  ("BT" form). m97-replica structure:
// 128x128 tile, BK=64, SINGLE-buffered LDS (32 KiB), 256 thr (4 waves, 64x64/wave),
// 2 barriers per K-tile. No manual waitcnt/schedule pinning: the compiler emits
// fine-grained lgkmcnt for ds_read->MFMA and drains vmcnt before each barrier;
// the drain stall is covered by CROSS-BLOCK wave overlap (3-4 blocks/CU via
// launch_bounds(256,3) + 32KB LDS) — m97/m114's mechanism, 874-912 TF measured.
// Swizzle: linear slot s of row r holds global slot s^(r&7) (0 conflicts R3/R5).
// MODE 0: C fp16   MODE 1: P=exp(acc*scale+mask) fp16 + row-sum partials (32/row)
// MODE 2: C fp32 = acc / lvec[z*M+row]
template<int MODE>
__global__ __launch_bounds__(256, 3)
void gemm_bt(const f16* __restrict__ Aall, const f16* __restrict__ Ball,
             void* __restrict__ Call,
             int M, int N, int K, int lda, int ldb, int ldc,
             long strideA, long strideB, long strideC,
             const float* __restrict__ maskAll, long strideMask,
             float* __restrict__ lvec, float scale)
{
  __shared__ __align__(16) f16 smA[BM * BK];   // 16 KB
  __shared__ __align__(16) f16 smB[BN * BK];   // 16 KB  -> 32 KiB total

  // T1: bijective XCD-aware remap (all grids have nwg % 8 == 0)
  unsigned gx = gridDim.x, gy = gridDim.y;
  unsigned id = (blockIdx.z * gy + blockIdx.y) * gx + blockIdx.x;
  unsigned nwg = gx * gy * gridDim.z;
  unsigned swz = (id & 7) * (nwg >> 3) + (id >> 3);
  unsigned bx = swz % gx, rem = swz / gx;
  unsigned by = rem % gy, bz = rem / gy;

  const int z = bz;
  const f16* A = Aall + (long)z * strideA;
  const f16* B = Ball + (long)z * strideB;

  const int tid  = threadIdx.x;
  const int wid  = tid >> 6;
  const int lane = tid & 63;
  const int wm = wid >> 1;        // 0..1 -> 64 rows of C
  const int wn = wid & 1;         // 0..1 -> 64 cols of C
  const int lr = lane & 15;
  const int g  = lane >> 4;       // k-slot 0..3 (8 f16 each)

  const long brow = (long)by * BM;
  const long bcol = (long)bx * BN;
  const int  nt   = K / BK;

  f32x4 acc[4][4] = {};

  // stage one 128x64 f16 tile (16 KB = 1024 chunks of 16B; 4 chunks/thread).
  // chunk c: row=c>>3, linear slot=c&7, global slot=(c&7)^(row&7).
  auto stA = [&](int t) {
    #pragma unroll
    for (int i = 0; i < 4; ++i) {
      int c  = i * 256 + tid;
      int r  = c >> 3;
      int sl = (c & 7) ^ (r & 7);
      gll16(A + (brow + r) * (long)lda + t * BK + sl * 8, &smA[c * 8]);
    }
  };
  auto stB = [&](int t) {
    #pragma unroll
    for (int i = 0; i < 4; ++i) {
      int c  = i * 256 + tid;
      int r  = c >> 3;
      int sl = (c & 7) ^ (r & 7);
      gll16(B + (bcol + r) * (long)ldb + t * BK + sl * 8, &smB[c * 8]);
    }
  };

  for (int t = 0; t < nt; ++t) {
    stA(t); stB(t);
    __syncthreads();                       // compiler drains vmcnt before s_barrier
    f16x8 af[8], bf[8];
    #pragma unroll
    for (int fm = 0; fm < 4; ++fm)
      #pragma unroll
      for (int ks = 0; ks < 2; ++ks) {
        int r = wm * 64 + fm * 16 + lr;
        af[fm * 2 + ks] = *(const f16x8*)(smA + r * BK + ((ks * 4 + g) ^ (r & 7)) * 8);
      }
    #pragma unroll
    for (int fn = 0; fn < 4; ++fn)
      #pragma unroll
      for (int ks = 0; ks < 2; ++ks) {
        int r = wn * 64 + fn * 16 + lr;
        bf[fn * 2 + ks] = *(const f16x8*)(smB + r * BK + ((ks * 4 + g) ^ (r & 7)) * 8);
      }
    #pragma unroll
    for (int fm = 0; fm < 4; ++fm)
      #pragma unroll
      for (int fn = 0; fn < 4; ++fn)
        #pragma unroll
        for (int ks = 0; ks < 2; ++ks)
          acc[fm][fn] = __builtin_amdgcn_mfma_f32_16x16x32_f16(
              af[fm * 2 + ks], bf[fn * 2 + ks], acc[fm][fn], 0, 0, 0);
    __syncthreads();                       // all reads done before next stage
  }

  // C/D layout (m89-verified): col = lane&15, row = (lane>>4)*4 + reg
  const int rb = (lane >> 4) * 4;

  if (MODE == 0) {
    f16* C = (f16*)Call + (long)z * strideC;
    #pragma unroll
    for (int m = 0; m < 4; ++m)
      #pragma unroll
      for (int j = 0; j < 4; ++j) {
        long grow = brow + wm * 64 + m * 16 + rb + j;
        #pragma unroll
        for (int n = 0; n < 4; ++n) {
          long gcol = bcol + wn * 64 + n * 16 + lr;
          C[grow * ldc + gcol] = (f16)acc[m][n][j];
        }
      }
  } else if (MODE == 1) {
    f16* C = (f16*)Call + (long)z * strideC;
    const float* mask = maskAll + (long)z * strideMask;
    #pragma unroll
    for (int m = 0; m < 4; ++m)
      #pragma unroll
      for (int j = 0; j < 4; ++j) {
        long grow = brow + wm * 64 + m * 16 + rb + j;
        float s = 0.f;
        #pragma unroll
        for (int n = 0; n < 4; ++n) {
          long gcol = bcol + wn * 64 + n * 16 + lr;
          float p = __expf(acc[m][n][j] * scale + mask[grow * ldc + gcol]);
          C[grow * ldc + gcol] = (f16)p;
          s += p;
        }
        s += __shfl_xor(s, 1);
        s += __shfl_xor(s, 2);
        s += __shfl_xor(s, 4);
        s += __shfl_xor(s, 8);
        if (lr == 0)
          lvec[((long)z * M + grow) * 32 + bx * 2 + wn] = s;
      }
  } else {
    float* C = (float*)Call + (long)z * strideC;
    #pragma unroll
    for (int m = 0; m < 4; ++m)
      #pragma unroll
      for (int j = 0; j < 4; ++j) {
        long grow = brow + wm * 64 + m * 16 + rb + j;
        float inv = 1.0f / lvec[(long)z * M + grow];
        #pragma unroll
        for (int n = 0; n < 4; ++n) {
          long gcol = bcol + wn * 64 + n * 16 + lr;
          C[grow * ldc + gcol] = acc[m][n][j] * inv;
        }
      }
  }
}

// one grid-strided kernel converting q,k,v,Wq,Wk,Wv fp32 -> fp16
__global__ void cvt_all(const float* __restrict__ q, const float* __restrict__ k,
                        const float* __restrict__ v, const float* __restrict__ Wq,
                        const float* __restrict__ Wk, const float* __restrict__ Wv,
                        f16* __restrict__ qf, f16* __restrict__ kf, f16* __restrict__ vf,
                        f16* __restrict__ Wqf, f16* __restrict__ Wkf, f16* __restrict__ Wvf)
{
  const long NQ4 = 4194304, NW4 = 262144;       // float4 counts
  const long total = 3 * NQ4 + 3 * NW4;
  for (long i = (long)blockIdx.x * blockDim.x + threadIdx.x; i < total;
       i += (long)gridDim.x * blockDim.x) {
    const float* src; f16* dst; long j = i;
    if      (j <     NQ4)           { src = q;  dst = qf; }
    else if (j < 2 * NQ4)           { src = k;  dst = kf;  j -= NQ4; }
    else if (j < 3 * NQ4)           { src = v;  dst = vf;  j -= 2 * NQ4; }
    else if (j < 3 * NQ4 + NW4)     { src = Wq; dst = Wqf; j -= 3 * NQ4; }
    else if (j < 3 * NQ4 + 2 * NW4) { src = Wk; dst = Wkf; j -= 3 * NQ4 + NW4; }
    else                            { src = Wv; dst = Wvf; j -= 3 * NQ4 + 2 * NW4; }
    float4 vv = ((const float4*)src)[j];
    f16x4 o;
    o[0] = (f16)vv.x; o[1] = (f16)vv.y; o[2] = (f16)vv.z; o[3] = (f16)vv.w;
    ((f16x4*)dst)[j] = o;
  }
}

__global__ void reduce_l(const float* __restrict__ lpart, float* __restrict__ lsum, int n) {
  int i = blockIdx.x * blockDim.x + threadIdx.x;
  if (i < n) {
    float s = 0.f;
    #pragma unroll
    for (int j = 0; j < 32; ++j) s += lpart[(long)i * 32 + j];
    lsum[i] = s;
  }
}

extern "C" void kernel_launch(void* const* d_in, const int* in_sizes, int n_in,
                              void* d_out, int out_size, void* d_ws, size_t ws_size,
                              hipStream_t stream)
{
  const float* q    = (const float*)d_in[0];
  const float* k    = (const float*)d_in[1];
  const float* v    = (const float*)d_in[2];
  const float* mask = (const float*)d_in[3];
  const float* Wq   = (const float*)d_in[4];
  const float* Wk   = (const float*)d_in[5];
  const float* Wv   = (const float*)d_in[6];
  float* out = (float*)d_out;
  char*  ws  = (char*)d_ws;

  // workspace layout (bytes); q/k/v fp16 region is dead after projections -> reused for P
  f16* qf  = (f16*)(ws + 0);            // 32 MB
  f16* kf  = (f16*)(ws + 33554432);     // 32 MB
  f16* vf  = (f16*)(ws + 67108864);     // 32 MB
  f16* Pm  = (f16*)(ws + 0);            // 64 MB (reuse of qf/kf/vf region)
  f16* Wqf = (f16*)(ws + 100663296);    // 2 MB
  f16* Wkf = (f16*)(ws + 102760448);
  f16* Wvf = (f16*)(ws + 104857600);
  f16* qp  = (f16*)(ws + 106954752);    // 32 MB
  f16* kp  = (f16*)(ws + 140509184);    // 32 MB
  f16* vpT = (f16*)(ws + 174063616);    // 32 MB  (stored H x J, i.e. transposed)
  float* lpart = (float*)(ws + 207618048); // 2 MB
  float* lsum  = (float*)(ws + 209715200); // 64 KB

  const long L = 2048, J = 2048, D = 1024, H = 1024;

  // 1) fp32 -> fp16 converts (single launch)
  cvt_all<<<dim3(2048), dim3(256), 0, stream>>>(q, k, v, Wq, Wk, Wv, qf, kf, vf, Wqf, Wkf, Wvf);

  // 2) projections
  // qp[bl,h] = sum_d q[bl,d] * Wq[h,d]     M=16384 N=1024 K=1024
  gemm_bt<0><<<dim3(1024 / BN, 16384 / BM, 1), dim3(256), 0, stream>>>(
      qf, Wqf, qp, 16384, 1024, 1024, 1024, 1024, 1024,
      0, 0, 0, nullptr, 0, nullptr, 0.f);
  // kp[bj,h] = sum_d k[bj,d] * Wk[h,d]
  gemm_bt<0><<<dim3(1024 / BN, 16384 / BM, 1), dim3(256), 0, stream>>>(
      kf, Wkf, kp, 16384, 1024, 1024, 1024, 1024, 1024,
      0, 0, 0, nullptr, 0, nullptr, 0.f);
  // vpT[b][h,j] = sum_d Wv[h,d] * v[b][j,d]   M=1024 N=2048 K=1024, batched over b
  gemm_bt<0><<<dim3(2048 / BN, 1024 / BM, 8), dim3(256), 0, stream>>>(
      Wvf, vf, vpT, 1024, 2048, 1024, 1024, 1024, 2048,
      0, J * D, H * J, nullptr, 0, nullptr, 0.f);

  // 3) P[b][l,j] = exp(qp.kp^T / 32 + mask), fp16, + row-sum partials
  gemm_bt<1><<<dim3(2048 / BN, 2048 / BM, 8), dim3(256), 0, stream>>>(
      qp, kp, Pm, 2048, 2048, 1024, 1024, 1024, 2048,
      L * H, J * H, L * J, mask, L * J, lpart, 0.03125f);

  reduce_l<<<dim3(16384 / 256), dim3(256), 0, stream>>>(lpart, lsum, 16384);

  // 4) out[b][l,h] = (sum_j P[l,j] * vpT[h,j]) / l[b,l]   M=2048 N=1024 K=2048
  gemm_bt<2><<<dim3(1024 / BN, 2048 / BM, 8), dim3(256), 0, stream>>>(
      Pm, vpT, out, 2048, 1024, 2048, 2048, 2048, 1024,
      L * J, H * J, L * H, nullptr, 0, lsum, 0.f);
}

// Round 9
// 337.392 us; speedup vs baseline: 1.3799x; 1.0651x over previous
//
#include <hip/hip_runtime.h>
#include <hip/hip_fp16.h>

typedef _Float16 f16;
typedef __attribute__((ext_vector_type(8))) _Float16 f16x8;
typedef __attribute__((ext_vector_type(4))) _Float16 f16x4;
typedef __attribute__((ext_vector_type(4))) float f32x4;

#define BM 128
#define BN 128
#define BK 64

__device__ __forceinline__ void gll16(const void* src, void* dst) {
  __builtin_amdgcn_global_load_lds((const __attribute__((address_space(1))) void*)src,
                                   (__attribute__((address_space(3))) void*)dst,
                                   16, 0, 0);
}

// C[m,n] = sum_k A[m,k] * B[n,k]  ("BT" form). m97-replica structure (R8, proven):
// 128x128 tile, BK=64, single-buffered 32 KiB LDS, 256 thr (4 waves, 64x64/wave),
// 2 barriers/K-tile; drain covered by 3 blocks/CU cross-block overlap (m114).
// Swizzle: linear slot s of row r holds global slot s^(r&7) (0 conflicts measured).
// MODE 0: C fp16   MODE 1: P=exp(acc*scale+mask) fp16 + row-sum partials (32/row)
// MODE 2: C fp32 = acc / lvec[z*M+row]
template<int MODE>
__global__ __launch_bounds__(256, 3)
void gemm_bt(const f16* __restrict__ Aall, const f16* __restrict__ Ball,
             void* __restrict__ Call,
             int M, int N, int K, int lda, int ldb, int ldc,
             long strideA, long strideB, long strideC,
             const float* __restrict__ maskAll, long strideMask,
             float* __restrict__ lvec, float scale)
{
  __shared__ __align__(16) f16 smA[BM * BK];   // 16 KB
  __shared__ __align__(16) f16 smB[BN * BK];   // 16 KB  -> 32 KiB total

  // T1: bijective XCD-aware remap (all grids have nwg % 8 == 0)
  unsigned gx = gridDim.x, gy = gridDim.y;
  unsigned id = (blockIdx.z * gy + blockIdx.y) * gx + blockIdx.x;
  unsigned nwg = gx * gy * gridDim.z;
  unsigned swz = (id & 7) * (nwg >> 3) + (id >> 3);
  unsigned bx = swz % gx, rem = swz / gx;
  unsigned by = rem % gy, bz = rem / gy;

  const int z = bz;
  const f16* A = Aall + (long)z * strideA;
  const f16* B = Ball + (long)z * strideB;

  const int tid  = threadIdx.x;
  const int wid  = tid >> 6;
  const int lane = tid & 63;
  const int wm = wid >> 1;        // 0..1 -> 64 rows of C
  const int wn = wid & 1;         // 0..1 -> 64 cols of C
  const int lr = lane & 15;
  const int g  = lane >> 4;       // k-slot 0..3 (8 f16 each)

  const long brow = (long)by * BM;
  const long bcol = (long)bx * BN;
  const int  nt   = K / BK;

  f32x4 acc[4][4] = {};

  // stage one 128x64 f16 tile (16 KB = 1024 chunks of 16B; 4 chunks/thread).
  auto stA = [&](int t) {
    #pragma unroll
    for (int i = 0; i < 4; ++i) {
      int c  = i * 256 + tid;
      int r  = c >> 3;
      int sl = (c & 7) ^ (r & 7);
      gll16(A + (brow + r) * (long)lda + t * BK + sl * 8, &smA[c * 8]);
    }
  };
  auto stB = [&](int t) {
    #pragma unroll
    for (int i = 0; i < 4; ++i) {
      int c  = i * 256 + tid;
      int r  = c >> 3;
      int sl = (c & 7) ^ (r & 7);
      gll16(B + (bcol + r) * (long)ldb + t * BK + sl * 8, &smB[c * 8]);
    }
  };

  for (int t = 0; t < nt; ++t) {
    stA(t); stB(t);
    __syncthreads();                       // compiler drains vmcnt before s_barrier
    f16x8 af[8], bf[8];
    #pragma unroll
    for (int fm = 0; fm < 4; ++fm)
      #pragma unroll
      for (int ks = 0; ks < 2; ++ks) {
        int r = wm * 64 + fm * 16 + lr;
        af[fm * 2 + ks] = *(const f16x8*)(smA + r * BK + ((ks * 4 + g) ^ (r & 7)) * 8);
      }
    #pragma unroll
    for (int fn = 0; fn < 4; ++fn)
      #pragma unroll
      for (int ks = 0; ks < 2; ++ks) {
        int r = wn * 64 + fn * 16 + lr;
        bf[fn * 2 + ks] = *(const f16x8*)(smB + r * BK + ((ks * 4 + g) ^ (r & 7)) * 8);
      }
    #pragma unroll
    for (int fm = 0; fm < 4; ++fm)
      #pragma unroll
      for (int fn = 0; fn < 4; ++fn)
        #pragma unroll
        for (int ks = 0; ks < 2; ++ks)
          acc[fm][fn] = __builtin_amdgcn_mfma_f32_16x16x32_f16(
              af[fm * 2 + ks], bf[fn * 2 + ks], acc[fm][fn], 0, 0, 0);
    __syncthreads();                       // all reads done before next stage
  }

  // C/D layout (m89-verified): col = lane&15, row = (lane>>4)*4 + reg
  const int rb = (lane >> 4) * 4;

  if (MODE == 0) {
    f16* C = (f16*)Call + (long)z * strideC;
    #pragma unroll
    for (int m = 0; m < 4; ++m)
      #pragma unroll
      for (int j = 0; j < 4; ++j) {
        long grow = brow + wm * 64 + m * 16 + rb + j;
        #pragma unroll
        for (int n = 0; n < 4; ++n) {
          long gcol = bcol + wn * 64 + n * 16 + lr;
          C[grow * ldc + gcol] = (f16)acc[m][n][j];
        }
      }
  } else if (MODE == 1) {
    f16* C = (f16*)Call + (long)z * strideC;
    const float* mask = maskAll + (long)z * strideMask;
    #pragma unroll
    for (int m = 0; m < 4; ++m)
      #pragma unroll
      for (int j = 0; j < 4; ++j) {
        long grow = brow + wm * 64 + m * 16 + rb + j;
        float s = 0.f;
        #pragma unroll
        for (int n = 0; n < 4; ++n) {
          long gcol = bcol + wn * 64 + n * 16 + lr;
          float p = __expf(acc[m][n][j] * scale + mask[grow * ldc + gcol]);
          C[grow * ldc + gcol] = (f16)p;
          s += p;
        }
        s += __shfl_xor(s, 1);
        s += __shfl_xor(s, 2);
        s += __shfl_xor(s, 4);
        s += __shfl_xor(s, 8);
        if (lr == 0)
          lvec[((long)z * M + grow) * 32 + bx * 2 + wn] = s;
      }
  } else {
    float* C = (float*)Call + (long)z * strideC;
    #pragma unroll
    for (int m = 0; m < 4; ++m)
      #pragma unroll
      for (int j = 0; j < 4; ++j) {
        long grow = brow + wm * 64 + m * 16 + rb + j;
        float inv = 1.0f / lvec[(long)z * M + grow];
        #pragma unroll
        for (int n = 0; n < 4; ++n) {
          long gcol = bcol + wn * 64 + n * 16 + lr;
          C[grow * ldc + gcol] = acc[m][n][j] * inv;
        }
      }
  }
}

// grid-strided fp32->fp16 convert: q, k, v, Wv  (Wq/Wk handled by transW)
__global__ void cvt_all(const float* __restrict__ q, const float* __restrict__ k,
                        const float* __restrict__ v, const float* __restrict__ Wv,
                        f16* __restrict__ qf, f16* __restrict__ kf, f16* __restrict__ vf,
                        f16* __restrict__ Wvf)
{
  const long NQ4 = 4194304, NW4 = 262144;       // float4 counts
  const long total = 3 * NQ4 + NW4;
  for (long i = (long)blockIdx.x * blockDim.x + threadIdx.x; i < total;
       i += (long)gridDim.x * blockDim.x) {
    const float* src; f16* dst; long j = i;
    if      (j <     NQ4) { src = q;  dst = qf; }
    else if (j < 2 * NQ4) { src = k;  dst = kf;  j -= NQ4; }
    else if (j < 3 * NQ4) { src = v;  dst = vf;  j -= 2 * NQ4; }
    else                  { src = Wv; dst = Wvf; j -= 3 * NQ4; }
    float4 vv = ((const float4*)src)[j];
    f16x4 o;
    o[0] = (f16)vv.x; o[1] = (f16)vv.y; o[2] = (f16)vv.z; o[3] = (f16)vv.w;
    ((f16x4*)dst)[j] = o;
  }
}

// 64x64-tile LDS transpose + fp32->fp16: WT[d][h] = (f16)W[h][d], for Wq and Wk.
__global__ void transW(const float* __restrict__ Wq, const float* __restrict__ Wk,
                       f16* __restrict__ WqT, f16* __restrict__ WkT)
{
  __shared__ f16 t[64][65];
  const float* W  = blockIdx.z ? Wk : Wq;
  f16*         WT = blockIdx.z ? WkT : WqT;
  const int h0 = blockIdx.y * 64, d0 = blockIdx.x * 64;
  const int tx = threadIdx.x & 15, ty = threadIdx.x >> 4;   // 16 x 16
  #pragma unroll
  for (int p = 0; p < 4; ++p) {
    int h = ty + p * 16;
    float4 vv = *(const float4*)(W + (long)(h0 + h) * 1024 + d0 + tx * 4);
    t[tx * 4 + 0][h] = (f16)vv.x;
    t[tx * 4 + 1][h] = (f16)vv.y;
    t[tx * 4 + 2][h] = (f16)vv.z;
    t[tx * 4 + 3][h] = (f16)vv.w;
  }
  __syncthreads();
  #pragma unroll
  for (int p = 0; p < 4; ++p) {
    int d = ty + p * 16;
    f16x4 o;
    o[0] = t[d][tx * 4 + 0];
    o[1] = t[d][tx * 4 + 1];
    o[2] = t[d][tx * 4 + 2];
    o[3] = t[d][tx * 4 + 3];
    *(f16x4*)(WT + (long)(d0 + d) * 1024 + h0 + tx * 4) = o;
  }
}

__global__ void reduce_l(const float* __restrict__ lpart, float* __restrict__ lsum, int n) {
  int i = blockIdx.x * blockDim.x + threadIdx.x;
  if (i < n) {
    float s = 0.f;
    #pragma unroll
    for (int j = 0; j < 32; ++j) s += lpart[(long)i * 32 + j];
    lsum[i] = s;
  }
}

extern "C" void kernel_launch(void* const* d_in, const int* in_sizes, int n_in,
                              void* d_out, int out_size, void* d_ws, size_t ws_size,
                              hipStream_t stream)
{
  const float* q    = (const float*)d_in[0];
  const float* k    = (const float*)d_in[1];
  const float* v    = (const float*)d_in[2];
  const float* mask = (const float*)d_in[3];
  const float* Wq   = (const float*)d_in[4];
  const float* Wk   = (const float*)d_in[5];
  const float* Wv   = (const float*)d_in[6];
  float* out = (float*)d_out;
  char*  ws  = (char*)d_ws;

  // workspace layout (bytes). qf and vf are dead after qg/vpT -> Pm overwrites
  // [0,64MB) = qf+vf. kf (needed by scores) lives above that region.
  f16*   qf    = (f16*)(ws + 0);           // 32 MB   (dead after qg)
  f16*   vf    = (f16*)(ws + 33554432);    // 32 MB   (dead after vpT)
  f16*   Pm    = (f16*)(ws + 0);           // 64 MB   (over qf+vf)
  f16*   kf    = (f16*)(ws + 67108864);    // 32 MB   (raw k fp16, read by scores)
  f16*   Wvf   = (f16*)(ws + 100663296);   // 2 MB
  f16*   WqT   = (f16*)(ws + 102760448);   // 2 MB    WqT[d][h]
  f16*   WkT   = (f16*)(ws + 104857600);   // 2 MB    WkT[d][h]
  f16*   Gt    = (f16*)(ws + 106954752);   // 2 MB    Gt[d'][d] = sum_h Wk[h,d']Wq[h,d]
  f16*   qg    = (f16*)(ws + 109051904);   // 32 MB   qg[l,d'] = sum_d q[l,d] G[d,d']
  f16*   vpT   = (f16*)(ws + 142606336);   // 32 MB   (stored H x J, transposed)
  float* lpart = (float*)(ws + 176160768); // 2 MB
  float* lsum  = (float*)(ws + 178257920); // 64 KB

  const long L = 2048, J = 2048, D = 1024, H = 1024;

  // 1) converts: q,k,v,Wv fp32->fp16 ; Wq,Wk fp32->fp16 TRANSPOSED
  cvt_all<<<dim3(2048), dim3(256), 0, stream>>>(q, k, v, Wv, qf, kf, vf, Wvf);
  transW<<<dim3(16, 16, 2), dim3(256), 0, stream>>>(Wq, Wk, WqT, WkT);

  // 2) Gt[d',d] = sum_h WkT[d',h] * WqT[d,h]   M=N=K=1024 (tiny, 2.1 GF)
  gemm_bt<0><<<dim3(1024 / BN, 1024 / BM, 1), dim3(256), 0, stream>>>(
      WkT, WqT, Gt, 1024, 1024, 1024, 1024, 1024, 1024,
      0, 0, 0, nullptr, 0, nullptr, 0.f);

  // 3) qg[l,d'] = sum_d qf[l,d] * Gt[d',d]   M=16384 N=1024 K=1024
  gemm_bt<0><<<dim3(1024 / BN, 16384 / BM, 1), dim3(256), 0, stream>>>(
      qf, Gt, qg, 16384, 1024, 1024, 1024, 1024, 1024,
      0, 0, 0, nullptr, 0, nullptr, 0.f);

  // 4) vpT[b][h,j] = sum_d Wv[h,d] * v[b][j,d]   M=1024 N=2048 K=1024, batched
  gemm_bt<0><<<dim3(2048 / BN, 1024 / BM, 8), dim3(256), 0, stream>>>(
      Wvf, vf, vpT, 1024, 2048, 1024, 1024, 1024, 2048,
      0, J * D, H * J, nullptr, 0, nullptr, 0.f);

  // 5) P[b][l,j] = exp(qg.kf^T / 32 + mask), fp16, + row-sum partials
  //    (scores = qp.kp^T by associativity: qg = q.Wq^T.Wk, kf = raw k)
  gemm_bt<1><<<dim3(2048 / BN, 2048 / BM, 8), dim3(256), 0, stream>>>(
      qg, kf, Pm, 2048, 2048, 1024, 1024, 1024, 2048,
      L * D, J * D, L * J, mask, L * J, lpart, 0.03125f);

  reduce_l<<<dim3(16384 / 256), dim3(256), 0, stream>>>(lpart, lsum, 16384);

  // 6) out[b][l,h] = (sum_j P[l,j] * vpT[h,j]) / l[b,l]   M=2048 N=1024 K=2048
  gemm_bt<2><<<dim3(1024 / BN, 2048 / BM, 8), dim3(256), 0, stream>>>(
      Pm, vpT, out, 2048, 1024, 2048, 2048, 2048, 1024,
      L * J, H * J, L * H, nullptr, 0, lsum, 0.f);
}